// Round 7
// baseline (160.942 us; speedup 1.0000x reference)
//
#include <hip/hip_runtime.h>
#include <hip/hip_fp16.h>
#include <math.h>

#define NB 8          // NUM_BINS
#define DD 32         // D
constexpr float TB   = 10.0f;   // TAIL_BOUND
constexpr float MBW  = 1e-3f;   // MIN_BIN_WIDTH
constexpr float MBH  = 1e-3f;   // MIN_BIN_HEIGHT
constexpr float MDER = 1e-3f;   // MIN_DERIVATIVE

typedef float f32x4 __attribute__((ext_vector_type(4)));

__device__ __forceinline__ float softplusf(float v) {
    return (v > 20.0f) ? v : log1pf(expf(v));
}

__global__ __launch_bounds__(256, 8) void mfb_kernel(
    const float* __restrict__ x,
    const float* __restrict__ uw,
    const float* __restrict__ uh,
    const float* __restrict__ ud,
    float* __restrict__ out,
    int n4)
{
    // 16B per-(dim,bin) record -> ONE ds_read_b128 per element:
    //   { m=invw f32, b=-cw*invw f32, half2(ch,h), half2(d0,d1) }
    // Row stride 9 float4s + XOR-on-bin key=(d>>2)&7 (2.6e6 conflict cycles,
    // measured rounds 4/6 — not the bottleneck).
    __shared__ float4 s_T[DD][NB + 1];
    __shared__ float  s_kn[DD][7];

    const int t = threadIdx.x;

    if (t < DD) {
        float posw[NB + 1], posh[NB + 1], dv[NB + 1];
        // ---- widths ----
        {
            float u[NB];
            float m = -1e30f;
            #pragma unroll
            for (int k = 0; k < NB; ++k) { u[k] = uw[t * NB + k]; m = fmaxf(m, u[k]); }
            float s = 0.0f;
            #pragma unroll
            for (int k = 0; k < NB; ++k) { u[k] = expf(u[k] - m); s += u[k]; }
            const float inv = 1.0f / s;
            posw[0] = -TB;
            float cum = 0.0f;
            #pragma unroll
            for (int k = 0; k < NB; ++k) {
                cum += MBW + (1.0f - MBW * (float)NB) * (u[k] * inv);
                posw[k + 1] = 2.0f * TB * cum - TB;
            }
            posw[NB] = TB;
        }
        // ---- heights ----
        {
            float u[NB];
            float m = -1e30f;
            #pragma unroll
            for (int k = 0; k < NB; ++k) { u[k] = uh[t * NB + k]; m = fmaxf(m, u[k]); }
            float s = 0.0f;
            #pragma unroll
            for (int k = 0; k < NB; ++k) { u[k] = expf(u[k] - m); s += u[k]; }
            const float inv = 1.0f / s;
            posh[0] = -TB;
            float cum = 0.0f;
            #pragma unroll
            for (int k = 0; k < NB; ++k) {
                cum += MBH + (1.0f - MBH * (float)NB) * (u[k] * inv);
                posh[k + 1] = 2.0f * TB * cum - TB;
            }
            posh[NB] = TB;
        }
        // ---- derivatives ----
        {
            const float c   = logf(expm1f(1.0f - MDER));
            const float bnd = MDER + softplusf(c);   // == 1.0 to fp precision
            dv[0]  = bnd;
            dv[NB] = bnd;
            #pragma unroll
            for (int k = 1; k < NB; ++k)
                dv[k] = MDER + softplusf(ud[t * (NB - 1) + (k - 1)]);
        }
        // ---- publish ----
        #pragma unroll
        for (int k = 0; k < 7; ++k) s_kn[t][k] = posw[k + 1];
        const int key = (t >> 2) & 7;
        #pragma unroll
        for (int b = 0; b < NB; ++b) {
            const float w    = posw[b + 1] - posw[b];
            const float invw = 1.0f / w;
            const unsigned u1 = ((unsigned)__half_as_ushort(__float2half_rn(posh[b + 1] - posh[b])) << 16)
                              |  (unsigned)__half_as_ushort(__float2half_rn(posh[b]));
            const unsigned u2 = ((unsigned)__half_as_ushort(__float2half_rn(dv[b + 1])) << 16)
                              |  (unsigned)__half_as_ushort(__float2half_rn(dv[b]));
            float4 T;
            T.x = invw;
            T.y = -posw[b] * invw;
            T.z = __uint_as_float(u1);
            T.w = __uint_as_float(u2);
            s_T[t][b ^ key] = T;
        }
    }
    __syncthreads();

    constexpr float HALF_LOG_2PI = 0.91893853320467274178f;
    constexpr float LN2          = 0.69314718055994530942f;

    const int g      = blockIdx.x * blockDim.x + t;
    const int stride = gridDim.x * blockDim.x;
    // stride*4 % 32 == 0 -> each thread's dim quad is fixed across iterations
    const int dbase  = (g * 4) & (DD - 1);
    const int key    = (dbase >> 2) & 7;

    float a0 = s_kn[dbase + 0][0], a1 = s_kn[dbase + 0][1], a2 = s_kn[dbase + 0][2],
          a3 = s_kn[dbase + 0][3], a4 = s_kn[dbase + 0][4], a5 = s_kn[dbase + 0][5],
          a6 = s_kn[dbase + 0][6];
    float b0 = s_kn[dbase + 1][0], b1 = s_kn[dbase + 1][1], b2 = s_kn[dbase + 1][2],
          b3 = s_kn[dbase + 1][3], b4 = s_kn[dbase + 1][4], b5 = s_kn[dbase + 1][5],
          b6 = s_kn[dbase + 1][6];
    float c0 = s_kn[dbase + 2][0], c1 = s_kn[dbase + 2][1], c2 = s_kn[dbase + 2][2],
          c3 = s_kn[dbase + 2][3], c4 = s_kn[dbase + 2][4], c5 = s_kn[dbase + 2][5],
          c6 = s_kn[dbase + 2][6];
    float e0 = s_kn[dbase + 3][0], e1 = s_kn[dbase + 3][1], e2 = s_kn[dbase + 3][2],
          e3 = s_kn[dbase + 3][3], e4 = s_kn[dbase + 3][4], e5 = s_kn[dbase + 3][5],
          e6 = s_kn[dbase + 3][6];

    const float4* __restrict__ r0 = &s_T[dbase + 0][0];
    const float4* __restrict__ r1 = &s_T[dbase + 1][0];
    const float4* __restrict__ r2 = &s_T[dbase + 2][0];
    const float4* __restrict__ r3 = &s_T[dbase + 3][0];

    auto evalone = [&](float xx,
                       float k0, float k1, float k2, float k3, float k4, float k5, float k6,
                       const float4* __restrict__ row) -> float {
        // tree-shaped accumulation shortens the dependency chain
        int i01 = ((xx >= k0) ? 1 : 0) + ((xx >= k1) ? 1 : 0);
        int i23 = ((xx >= k2) ? 1 : 0) + ((xx >= k3) ? 1 : 0);
        int i45 = ((xx >= k4) ? 1 : 0) + ((xx >= k5) ? 1 : 0);
        int i6  = ((xx >= k6) ? 1 : 0);
        int idx = (i01 + i23) + (i45 + i6);

        const float4 T = row[idx ^ key];   // one ds_read_b128

        const unsigned u1 = __float_as_uint(T.z);
        const unsigned u2 = __float_as_uint(T.w);
        const float ch = __half2float(__ushort_as_half((unsigned short)(u1 & 0xffffu)));
        const float h  = __half2float(__ushort_as_half((unsigned short)(u1 >> 16)));
        const float d0 = __half2float(__ushort_as_half((unsigned short)(u2 & 0xffffu)));
        const float d1 = __half2float(__ushort_as_half((unsigned short)(u2 >> 16)));

        const float xc    = fminf(fmaxf(xx, -TB), TB);
        const float theta = fmaf(xc, T.x, T.y);
        const float delta = h * T.x;                              // h*invw
        const float B     = h * d0;
        const float A     = fmaf(h, delta, -B);                   // h*(delta-d0)
        const float s2    = (d0 + d1) - (delta + delta);
        const float u     = fmaf(-theta, theta, theta);           // θ(1-θ)
        const float den   = fmaf(s2, u, delta);
        const float rden  = __builtin_amdgcn_rcpf(den);
        const float num1  = theta * fmaf(theta, A, B);
        const float zin   = fmaf(num1, rden, ch);
        const float dmd   = delta - d0;
        const float poly  = fmaf(fmaf(s2, theta, dmd + dmd), theta, d0);
        const float ee    = delta * rden;
        const float larg  = poly * (ee * ee);
        const float lg2   = __log2f(larg);
        // outside [-B,B]: θ∈{0,1} to 1ulp -> larg ~= boundary deriv = 1 -> lg2≈0
        const float z  = (fabsf(xx) <= TB) ? zin : xx;
        const float ld = fmaf(lg2, LN2, -HALF_LOG_2PI);
        return fmaf(z * z, -0.5f, ld);
    };

    auto eval4 = [&](f32x4 xv) -> f32x4 {
        f32x4 r;
        r.x = evalone(xv.x, a0, a1, a2, a3, a4, a5, a6, r0);
        r.y = evalone(xv.y, b0, b1, b2, b3, b4, b5, b6, r1);
        r.z = evalone(xv.z, c0, c1, c2, c3, c4, c5, c6, r2);
        r.w = evalone(xv.w, e0, e1, e2, e3, e4, e5, e6, r3);
        return r;
    };

    const f32x4* __restrict__ x4 = reinterpret_cast<const f32x4*>(x);
    f32x4* __restrict__ o4 = reinterpret_cast<f32x4*>(out);

    int i = g;
    // 4x unroll: 4 independent 16B loads in flight (MLP), compute+store each
    // quad as it resolves. Non-temporal stores keep the 131MB write stream
    // from evicting x's L3 residency.
    for (; i + 3 * stride < n4; i += 4 * stride) {
        const f32x4 xv0 = x4[i];
        const f32x4 xv1 = x4[i + stride];
        const f32x4 xv2 = x4[i + 2 * stride];
        const f32x4 xv3 = x4[i + 3 * stride];
        __builtin_nontemporal_store(eval4(xv0), &o4[i]);
        __builtin_nontemporal_store(eval4(xv1), &o4[i + stride]);
        __builtin_nontemporal_store(eval4(xv2), &o4[i + 2 * stride]);
        __builtin_nontemporal_store(eval4(xv3), &o4[i + 3 * stride]);
    }
    for (; i < n4; i += stride) {
        const f32x4 xv0 = x4[i];
        __builtin_nontemporal_store(eval4(xv0), &o4[i]);
    }
}

extern "C" void kernel_launch(void* const* d_in, const int* in_sizes, int n_in,
                              void* d_out, int out_size, void* d_ws, size_t ws_size,
                              hipStream_t stream) {
    const float* x  = (const float*)d_in[0];
    const float* uw = (const float*)d_in[1];
    const float* uh = (const float*)d_in[2];
    const float* ud = (const float*)d_in[3];
    float* out = (float*)d_out;

    const int n4 = in_sizes[0] / 4;                 // N*D/4 float4 elements
    int blocks = (n4 + 255) / 256;
    if (blocks > 2048) blocks = 2048;

    mfb_kernel<<<blocks, 256, 0, stream>>>(x, uw, uh, ud, out, n4);
}

// Round 8
// 61.696 us; speedup vs baseline: 2.6086x; 2.6086x over previous
//
#include <hip/hip_runtime.h>
#include <hip/hip_fp16.h>
#include <math.h>

#define NB 8          // NUM_BINS
#define DD 32         // D
constexpr float TB   = 10.0f;   // TAIL_BOUND
constexpr float MBW  = 1e-3f;   // MIN_BIN_WIDTH
constexpr float MBH  = 1e-3f;   // MIN_BIN_HEIGHT
constexpr float MDER = 1e-3f;   // MIN_DERIVATIVE

typedef float f32x4 __attribute__((ext_vector_type(4)));

__device__ __forceinline__ float softplusf(float v) {
    return (v > 20.0f) ? v : log1pf(expf(v));
}

__global__ __launch_bounds__(256, 4) void mfb_kernel(
    const float* __restrict__ x,
    const float* __restrict__ uw,
    const float* __restrict__ uh,
    const float* __restrict__ ud,
    float* __restrict__ out,
    int n4)
{
    // 16B per-(dim,bin) record -> ONE ds_read_b128 per element:
    //   { m=invw f32, b=-cw*invw f32, half2(ch,h), half2(d0,d1) }
    // Row stride 9 float4s + XOR-on-bin key=(d>>2)&7 (2.6e6 conflict cycles,
    // measured rounds 4/6 — not the bottleneck).
    // launch_bounds(256,4): round 7 proved (256,8)/32-VGPR spills the
    // unrolled quads to scratch (FETCH 66->354MB, WRITE 131->256MB).
    __shared__ float4 s_T[DD][NB + 1];
    __shared__ float  s_kn[DD][7];

    const int t = threadIdx.x;

    if (t < DD) {
        float posw[NB + 1], posh[NB + 1], dv[NB + 1];
        // ---- widths ----
        {
            float u[NB];
            float m = -1e30f;
            #pragma unroll
            for (int k = 0; k < NB; ++k) { u[k] = uw[t * NB + k]; m = fmaxf(m, u[k]); }
            float s = 0.0f;
            #pragma unroll
            for (int k = 0; k < NB; ++k) { u[k] = expf(u[k] - m); s += u[k]; }
            const float inv = 1.0f / s;
            posw[0] = -TB;
            float cum = 0.0f;
            #pragma unroll
            for (int k = 0; k < NB; ++k) {
                cum += MBW + (1.0f - MBW * (float)NB) * (u[k] * inv);
                posw[k + 1] = 2.0f * TB * cum - TB;
            }
            posw[NB] = TB;
        }
        // ---- heights ----
        {
            float u[NB];
            float m = -1e30f;
            #pragma unroll
            for (int k = 0; k < NB; ++k) { u[k] = uh[t * NB + k]; m = fmaxf(m, u[k]); }
            float s = 0.0f;
            #pragma unroll
            for (int k = 0; k < NB; ++k) { u[k] = expf(u[k] - m); s += u[k]; }
            const float inv = 1.0f / s;
            posh[0] = -TB;
            float cum = 0.0f;
            #pragma unroll
            for (int k = 0; k < NB; ++k) {
                cum += MBH + (1.0f - MBH * (float)NB) * (u[k] * inv);
                posh[k + 1] = 2.0f * TB * cum - TB;
            }
            posh[NB] = TB;
        }
        // ---- derivatives ----
        {
            const float c   = logf(expm1f(1.0f - MDER));
            const float bnd = MDER + softplusf(c);   // == 1.0 to fp precision
            dv[0]  = bnd;
            dv[NB] = bnd;
            #pragma unroll
            for (int k = 1; k < NB; ++k)
                dv[k] = MDER + softplusf(ud[t * (NB - 1) + (k - 1)]);
        }
        // ---- publish ----
        #pragma unroll
        for (int k = 0; k < 7; ++k) s_kn[t][k] = posw[k + 1];
        const int key = (t >> 2) & 7;
        #pragma unroll
        for (int b = 0; b < NB; ++b) {
            const float w    = posw[b + 1] - posw[b];
            const float invw = 1.0f / w;
            const unsigned u1 = ((unsigned)__half_as_ushort(__float2half_rn(posh[b + 1] - posh[b])) << 16)
                              |  (unsigned)__half_as_ushort(__float2half_rn(posh[b]));
            const unsigned u2 = ((unsigned)__half_as_ushort(__float2half_rn(dv[b + 1])) << 16)
                              |  (unsigned)__half_as_ushort(__float2half_rn(dv[b]));
            float4 T;
            T.x = invw;
            T.y = -posw[b] * invw;
            T.z = __uint_as_float(u1);
            T.w = __uint_as_float(u2);
            s_T[t][b ^ key] = T;
        }
    }
    __syncthreads();

    constexpr float HALF_LOG_2PI = 0.91893853320467274178f;
    constexpr float LN2          = 0.69314718055994530942f;

    const int g      = blockIdx.x * blockDim.x + t;
    const int stride = gridDim.x * blockDim.x;
    // stride*4 % 32 == 0 -> each thread's dim quad is fixed across iterations
    const int dbase  = (g * 4) & (DD - 1);
    const int key    = (dbase >> 2) & 7;

    float a0 = s_kn[dbase + 0][0], a1 = s_kn[dbase + 0][1], a2 = s_kn[dbase + 0][2],
          a3 = s_kn[dbase + 0][3], a4 = s_kn[dbase + 0][4], a5 = s_kn[dbase + 0][5],
          a6 = s_kn[dbase + 0][6];
    float b0 = s_kn[dbase + 1][0], b1 = s_kn[dbase + 1][1], b2 = s_kn[dbase + 1][2],
          b3 = s_kn[dbase + 1][3], b4 = s_kn[dbase + 1][4], b5 = s_kn[dbase + 1][5],
          b6 = s_kn[dbase + 1][6];
    float c0 = s_kn[dbase + 2][0], c1 = s_kn[dbase + 2][1], c2 = s_kn[dbase + 2][2],
          c3 = s_kn[dbase + 2][3], c4 = s_kn[dbase + 2][4], c5 = s_kn[dbase + 2][5],
          c6 = s_kn[dbase + 2][6];
    float e0 = s_kn[dbase + 3][0], e1 = s_kn[dbase + 3][1], e2 = s_kn[dbase + 3][2],
          e3 = s_kn[dbase + 3][3], e4 = s_kn[dbase + 3][4], e5 = s_kn[dbase + 3][5],
          e6 = s_kn[dbase + 3][6];

    const float4* __restrict__ r0 = &s_T[dbase + 0][0];
    const float4* __restrict__ r1 = &s_T[dbase + 1][0];
    const float4* __restrict__ r2 = &s_T[dbase + 2][0];
    const float4* __restrict__ r3 = &s_T[dbase + 3][0];

    auto evalone = [&](float xx,
                       float k0, float k1, float k2, float k3, float k4, float k5, float k6,
                       const float4* __restrict__ row) -> float {
        // tree-shaped accumulation shortens the dependency chain
        int i01 = ((xx >= k0) ? 1 : 0) + ((xx >= k1) ? 1 : 0);
        int i23 = ((xx >= k2) ? 1 : 0) + ((xx >= k3) ? 1 : 0);
        int i45 = ((xx >= k4) ? 1 : 0) + ((xx >= k5) ? 1 : 0);
        int i6  = ((xx >= k6) ? 1 : 0);
        int idx = (i01 + i23) + (i45 + i6);

        const float4 T = row[idx ^ key];   // one ds_read_b128

        const unsigned u1 = __float_as_uint(T.z);
        const unsigned u2 = __float_as_uint(T.w);
        const float ch = __half2float(__ushort_as_half((unsigned short)(u1 & 0xffffu)));
        const float h  = __half2float(__ushort_as_half((unsigned short)(u1 >> 16)));
        const float d0 = __half2float(__ushort_as_half((unsigned short)(u2 & 0xffffu)));
        const float d1 = __half2float(__ushort_as_half((unsigned short)(u2 >> 16)));

        const float xc    = fminf(fmaxf(xx, -TB), TB);
        const float theta = fmaf(xc, T.x, T.y);
        const float delta = h * T.x;                              // h*invw
        const float B     = h * d0;
        const float A     = fmaf(h, delta, -B);                   // h*(delta-d0)
        const float s2    = (d0 + d1) - (delta + delta);
        const float u     = fmaf(-theta, theta, theta);           // θ(1-θ)
        const float den   = fmaf(s2, u, delta);
        const float rden  = __builtin_amdgcn_rcpf(den);
        const float num1  = theta * fmaf(theta, A, B);
        const float zin   = fmaf(num1, rden, ch);
        const float dmd   = delta - d0;
        const float poly  = fmaf(fmaf(s2, theta, dmd + dmd), theta, d0);
        const float ee    = delta * rden;
        const float larg  = poly * (ee * ee);
        const float lg2   = __log2f(larg);
        // outside [-B,B]: θ∈{0,1} to 1ulp -> larg ~= boundary deriv = 1 -> lg2≈0
        const float z  = (fabsf(xx) <= TB) ? zin : xx;
        const float ld = fmaf(lg2, LN2, -HALF_LOG_2PI);
        return fmaf(z * z, -0.5f, ld);
    };

    auto eval4 = [&](f32x4 xv) -> f32x4 {
        f32x4 r;
        r.x = evalone(xv.x, a0, a1, a2, a3, a4, a5, a6, r0);
        r.y = evalone(xv.y, b0, b1, b2, b3, b4, b5, b6, r1);
        r.z = evalone(xv.z, c0, c1, c2, c3, c4, c5, c6, r2);
        r.w = evalone(xv.w, e0, e1, e2, e3, e4, e5, e6, r3);
        return r;
    };

    const f32x4* __restrict__ x4 = reinterpret_cast<const f32x4*>(x);
    f32x4* __restrict__ o4 = reinterpret_cast<f32x4*>(out);

    int i = g;
    // 4x unroll: 4 independent 16B loads in flight per thread (MLP). With the
    // 128-VGPR budget these stay in registers (round 7's 32-VGPR cap spilled).
    for (; i + 3 * stride < n4; i += 4 * stride) {
        const f32x4 xv0 = x4[i];
        const f32x4 xv1 = x4[i + stride];
        const f32x4 xv2 = x4[i + 2 * stride];
        const f32x4 xv3 = x4[i + 3 * stride];
        o4[i]              = eval4(xv0);
        o4[i + stride]     = eval4(xv1);
        o4[i + 2 * stride] = eval4(xv2);
        o4[i + 3 * stride] = eval4(xv3);
    }
    for (; i < n4; i += stride) {
        const f32x4 xv0 = x4[i];
        o4[i] = eval4(xv0);
    }
}

extern "C" void kernel_launch(void* const* d_in, const int* in_sizes, int n_in,
                              void* d_out, int out_size, void* d_ws, size_t ws_size,
                              hipStream_t stream) {
    const float* x  = (const float*)d_in[0];
    const float* uw = (const float*)d_in[1];
    const float* uh = (const float*)d_in[2];
    const float* ud = (const float*)d_in[3];
    float* out = (float*)d_out;

    const int n4 = in_sizes[0] / 4;                 // N*D/4 float4 elements
    int blocks = (n4 + 255) / 256;
    if (blocks > 2048) blocks = 2048;

    mfb_kernel<<<blocks, 256, 0, stream>>>(x, uw, uh, ud, out, n4);
}

// Round 9
// 58.739 us; speedup vs baseline: 2.7400x; 1.0503x over previous
//
#include <hip/hip_runtime.h>
#include <hip/hip_fp16.h>
#include <math.h>

#define NB 8          // NUM_BINS
#define DD 32         // D
constexpr float TB   = 10.0f;   // TAIL_BOUND
constexpr float MBW  = 1e-3f;   // MIN_BIN_WIDTH
constexpr float MBH  = 1e-3f;   // MIN_BIN_HEIGHT
constexpr float MDER = 1e-3f;   // MIN_DERIVATIVE

typedef float f32x4 __attribute__((ext_vector_type(4)));

__device__ __forceinline__ float softplusf(float v) {
    return (v > 20.0f) ? v : log1pf(expf(v));
}

__global__ __launch_bounds__(256, 4) void mfb_kernel(
    const float* __restrict__ x,
    const float* __restrict__ uw,
    const float* __restrict__ uh,
    const float* __restrict__ ud,
    float* __restrict__ out,
    int n4)
{
    // Round-6 structure exactly (best: 59.1us), single change: non-temporal
    // stores. Rationale: x(128MB)+out(128MB) exactly fill the 256MB L3; the
    // write stream evicts half of x every pass (measured FETCH=65.7MB = x/2).
    // nt-stores bypass L3 -> x stays fully resident -> HBM reads ~0 and read
    // latency drops to L3-class. Single-variable test (round 7 was confounded
    // by VGPR spill).
    __shared__ float4 s_T[DD][NB + 1];
    __shared__ float  s_kn[DD][7];

    const int t = threadIdx.x;

    if (t < DD) {
        float posw[NB + 1], posh[NB + 1], dv[NB + 1];
        // ---- widths ----
        {
            float u[NB];
            float m = -1e30f;
            #pragma unroll
            for (int k = 0; k < NB; ++k) { u[k] = uw[t * NB + k]; m = fmaxf(m, u[k]); }
            float s = 0.0f;
            #pragma unroll
            for (int k = 0; k < NB; ++k) { u[k] = expf(u[k] - m); s += u[k]; }
            const float inv = 1.0f / s;
            posw[0] = -TB;
            float cum = 0.0f;
            #pragma unroll
            for (int k = 0; k < NB; ++k) {
                cum += MBW + (1.0f - MBW * (float)NB) * (u[k] * inv);
                posw[k + 1] = 2.0f * TB * cum - TB;
            }
            posw[NB] = TB;
        }
        // ---- heights ----
        {
            float u[NB];
            float m = -1e30f;
            #pragma unroll
            for (int k = 0; k < NB; ++k) { u[k] = uh[t * NB + k]; m = fmaxf(m, u[k]); }
            float s = 0.0f;
            #pragma unroll
            for (int k = 0; k < NB; ++k) { u[k] = expf(u[k] - m); s += u[k]; }
            const float inv = 1.0f / s;
            posh[0] = -TB;
            float cum = 0.0f;
            #pragma unroll
            for (int k = 0; k < NB; ++k) {
                cum += MBH + (1.0f - MBH * (float)NB) * (u[k] * inv);
                posh[k + 1] = 2.0f * TB * cum - TB;
            }
            posh[NB] = TB;
        }
        // ---- derivatives ----
        {
            const float c   = logf(expm1f(1.0f - MDER));
            const float bnd = MDER + softplusf(c);   // == 1.0 to fp precision
            dv[0]  = bnd;
            dv[NB] = bnd;
            #pragma unroll
            for (int k = 1; k < NB; ++k)
                dv[k] = MDER + softplusf(ud[t * (NB - 1) + (k - 1)]);
        }
        // ---- publish ----
        #pragma unroll
        for (int k = 0; k < 7; ++k) s_kn[t][k] = posw[k + 1];
        const int key = (t >> 2) & 7;
        #pragma unroll
        for (int b = 0; b < NB; ++b) {
            const float w    = posw[b + 1] - posw[b];
            const float invw = 1.0f / w;
            const unsigned u1 = ((unsigned)__half_as_ushort(__float2half_rn(posh[b + 1] - posh[b])) << 16)
                              |  (unsigned)__half_as_ushort(__float2half_rn(posh[b]));
            const unsigned u2 = ((unsigned)__half_as_ushort(__float2half_rn(dv[b + 1])) << 16)
                              |  (unsigned)__half_as_ushort(__float2half_rn(dv[b]));
            float4 T;
            T.x = invw;
            T.y = -posw[b] * invw;
            T.z = __uint_as_float(u1);
            T.w = __uint_as_float(u2);
            s_T[t][b ^ key] = T;
        }
    }
    __syncthreads();

    constexpr float HALF_LOG_2PI = 0.91893853320467274178f;
    constexpr float LN2          = 0.69314718055994530942f;

    const int g      = blockIdx.x * blockDim.x + t;
    const int stride = gridDim.x * blockDim.x;
    // stride*4 % 32 == 0 -> each thread's dim quad is fixed across iterations
    const int dbase  = (g * 4) & (DD - 1);
    const int key    = (dbase >> 2) & 7;

    float a0 = s_kn[dbase + 0][0], a1 = s_kn[dbase + 0][1], a2 = s_kn[dbase + 0][2],
          a3 = s_kn[dbase + 0][3], a4 = s_kn[dbase + 0][4], a5 = s_kn[dbase + 0][5],
          a6 = s_kn[dbase + 0][6];
    float b0 = s_kn[dbase + 1][0], b1 = s_kn[dbase + 1][1], b2 = s_kn[dbase + 1][2],
          b3 = s_kn[dbase + 1][3], b4 = s_kn[dbase + 1][4], b5 = s_kn[dbase + 1][5],
          b6 = s_kn[dbase + 1][6];
    float c0 = s_kn[dbase + 2][0], c1 = s_kn[dbase + 2][1], c2 = s_kn[dbase + 2][2],
          c3 = s_kn[dbase + 2][3], c4 = s_kn[dbase + 2][4], c5 = s_kn[dbase + 2][5],
          c6 = s_kn[dbase + 2][6];
    float e0 = s_kn[dbase + 3][0], e1 = s_kn[dbase + 3][1], e2 = s_kn[dbase + 3][2],
          e3 = s_kn[dbase + 3][3], e4 = s_kn[dbase + 3][4], e5 = s_kn[dbase + 3][5],
          e6 = s_kn[dbase + 3][6];

    const float4* __restrict__ r0 = &s_T[dbase + 0][0];
    const float4* __restrict__ r1 = &s_T[dbase + 1][0];
    const float4* __restrict__ r2 = &s_T[dbase + 2][0];
    const float4* __restrict__ r3 = &s_T[dbase + 3][0];

    auto evalone = [&](float xx,
                       float k0, float k1, float k2, float k3, float k4, float k5, float k6,
                       const float4* __restrict__ row) -> float {
        // tree-shaped accumulation shortens the dependency chain
        int i01 = ((xx >= k0) ? 1 : 0) + ((xx >= k1) ? 1 : 0);
        int i23 = ((xx >= k2) ? 1 : 0) + ((xx >= k3) ? 1 : 0);
        int i45 = ((xx >= k4) ? 1 : 0) + ((xx >= k5) ? 1 : 0);
        int i6  = ((xx >= k6) ? 1 : 0);
        int idx = (i01 + i23) + (i45 + i6);

        const float4 T = row[idx ^ key];   // one ds_read_b128

        const unsigned u1 = __float_as_uint(T.z);
        const unsigned u2 = __float_as_uint(T.w);
        const float ch = __half2float(__ushort_as_half((unsigned short)(u1 & 0xffffu)));
        const float h  = __half2float(__ushort_as_half((unsigned short)(u1 >> 16)));
        const float d0 = __half2float(__ushort_as_half((unsigned short)(u2 & 0xffffu)));
        const float d1 = __half2float(__ushort_as_half((unsigned short)(u2 >> 16)));

        const float xc    = fminf(fmaxf(xx, -TB), TB);
        const float theta = fmaf(xc, T.x, T.y);
        const float delta = h * T.x;                              // h*invw
        const float B     = h * d0;
        const float A     = fmaf(h, delta, -B);                   // h*(delta-d0)
        const float s2    = (d0 + d1) - (delta + delta);
        const float u     = fmaf(-theta, theta, theta);           // θ(1-θ)
        const float den   = fmaf(s2, u, delta);
        const float rden  = __builtin_amdgcn_rcpf(den);
        const float num1  = theta * fmaf(theta, A, B);
        const float zin   = fmaf(num1, rden, ch);
        const float dmd   = delta - d0;
        const float poly  = fmaf(fmaf(s2, theta, dmd + dmd), theta, d0);
        const float ee    = delta * rden;
        const float larg  = poly * (ee * ee);
        const float lg2   = __log2f(larg);
        // outside [-B,B]: θ∈{0,1} to 1ulp -> larg ~= boundary deriv = 1 -> lg2≈0
        const float z  = (fabsf(xx) <= TB) ? zin : xx;
        const float ld = fmaf(lg2, LN2, -HALF_LOG_2PI);
        return fmaf(z * z, -0.5f, ld);
    };

    auto eval4 = [&](f32x4 xv) -> f32x4 {
        f32x4 r;
        r.x = evalone(xv.x, a0, a1, a2, a3, a4, a5, a6, r0);
        r.y = evalone(xv.y, b0, b1, b2, b3, b4, b5, b6, r1);
        r.z = evalone(xv.z, c0, c1, c2, c3, c4, c5, c6, r2);
        r.w = evalone(xv.w, e0, e1, e2, e3, e4, e5, e6, r3);
        return r;
    };

    const f32x4* __restrict__ x4 = reinterpret_cast<const f32x4*>(x);
    f32x4* __restrict__ o4 = reinterpret_cast<f32x4*>(out);

    int i = g;
    for (; i + stride < n4; i += 2 * stride) {
        const f32x4 xa = x4[i];
        const f32x4 xb = x4[i + stride];
        __builtin_nontemporal_store(eval4(xa), &o4[i]);
        __builtin_nontemporal_store(eval4(xb), &o4[i + stride]);
    }
    for (; i < n4; i += stride) {
        const f32x4 xa = x4[i];
        __builtin_nontemporal_store(eval4(xa), &o4[i]);
    }
}

extern "C" void kernel_launch(void* const* d_in, const int* in_sizes, int n_in,
                              void* d_out, int out_size, void* d_ws, size_t ws_size,
                              hipStream_t stream) {
    const float* x  = (const float*)d_in[0];
    const float* uw = (const float*)d_in[1];
    const float* uh = (const float*)d_in[2];
    const float* ud = (const float*)d_in[3];
    float* out = (float*)d_out;

    const int n4 = in_sizes[0] / 4;                 // N*D/4 float4 elements
    int blocks = (n4 + 255) / 256;
    if (blocks > 2048) blocks = 2048;

    mfb_kernel<<<blocks, 256, 0, stream>>>(x, uw, uh, ud, out, n4);
}

// Round 10
// 58.010 us; speedup vs baseline: 2.7744x; 1.0126x over previous
//
#include <hip/hip_runtime.h>
#include <hip/hip_fp16.h>
#include <math.h>

#define NB 8          // NUM_BINS
#define DD 32         // D
constexpr float TB   = 10.0f;   // TAIL_BOUND
constexpr float MBW  = 1e-3f;   // MIN_BIN_WIDTH
constexpr float MBH  = 1e-3f;   // MIN_BIN_HEIGHT
constexpr float MDER = 1e-3f;   // MIN_DERIVATIVE

typedef float f32x4 __attribute__((ext_vector_type(4)));

__device__ __forceinline__ float softplusf(float v) {
    return (v > 20.0f) ? v : log1pf(expf(v));
}

__global__ __launch_bounds__(256, 4) void mfb_kernel(
    const float* __restrict__ x,
    const float* __restrict__ uw,
    const float* __restrict__ uh,
    const float* __restrict__ ud,
    float* __restrict__ out,
    int n4)
{
    // Round-6/9 data structure (best), new LOOP structure:
    //   * rolling 1-deep register prefetch: load[j+1] issues BEFORE compute[j]
    //     so every load has a full compute phase of latency cover
    //   * per-wave rotated start (wave_id % nI) de-phases the waves' memory
    //     bursts across the CU (rounds 6/8/9 all ran loads/compute in lockstep:
    //     VALU ~51% + HBM ~53% summed to the runtime instead of overlapping)
    __shared__ float4 s_T[DD][NB + 1];
    __shared__ float  s_kn[DD][7];

    const int t = threadIdx.x;

    if (t < DD) {
        float posw[NB + 1], posh[NB + 1], dv[NB + 1];
        // ---- widths ----
        {
            float u[NB];
            float m = -1e30f;
            #pragma unroll
            for (int k = 0; k < NB; ++k) { u[k] = uw[t * NB + k]; m = fmaxf(m, u[k]); }
            float s = 0.0f;
            #pragma unroll
            for (int k = 0; k < NB; ++k) { u[k] = expf(u[k] - m); s += u[k]; }
            const float inv = 1.0f / s;
            posw[0] = -TB;
            float cum = 0.0f;
            #pragma unroll
            for (int k = 0; k < NB; ++k) {
                cum += MBW + (1.0f - MBW * (float)NB) * (u[k] * inv);
                posw[k + 1] = 2.0f * TB * cum - TB;
            }
            posw[NB] = TB;
        }
        // ---- heights ----
        {
            float u[NB];
            float m = -1e30f;
            #pragma unroll
            for (int k = 0; k < NB; ++k) { u[k] = uh[t * NB + k]; m = fmaxf(m, u[k]); }
            float s = 0.0f;
            #pragma unroll
            for (int k = 0; k < NB; ++k) { u[k] = expf(u[k] - m); s += u[k]; }
            const float inv = 1.0f / s;
            posh[0] = -TB;
            float cum = 0.0f;
            #pragma unroll
            for (int k = 0; k < NB; ++k) {
                cum += MBH + (1.0f - MBH * (float)NB) * (u[k] * inv);
                posh[k + 1] = 2.0f * TB * cum - TB;
            }
            posh[NB] = TB;
        }
        // ---- derivatives ----
        {
            const float c   = logf(expm1f(1.0f - MDER));
            const float bnd = MDER + softplusf(c);   // == 1.0 to fp precision
            dv[0]  = bnd;
            dv[NB] = bnd;
            #pragma unroll
            for (int k = 1; k < NB; ++k)
                dv[k] = MDER + softplusf(ud[t * (NB - 1) + (k - 1)]);
        }
        // ---- publish ----
        #pragma unroll
        for (int k = 0; k < 7; ++k) s_kn[t][k] = posw[k + 1];
        const int key = (t >> 2) & 7;
        #pragma unroll
        for (int b = 0; b < NB; ++b) {
            const float w    = posw[b + 1] - posw[b];
            const float invw = 1.0f / w;
            const unsigned u1 = ((unsigned)__half_as_ushort(__float2half_rn(posh[b + 1] - posh[b])) << 16)
                              |  (unsigned)__half_as_ushort(__float2half_rn(posh[b]));
            const unsigned u2 = ((unsigned)__half_as_ushort(__float2half_rn(dv[b + 1])) << 16)
                              |  (unsigned)__half_as_ushort(__float2half_rn(dv[b]));
            float4 T;
            T.x = invw;
            T.y = -posw[b] * invw;
            T.z = __uint_as_float(u1);
            T.w = __uint_as_float(u2);
            s_T[t][b ^ key] = T;
        }
    }
    __syncthreads();

    constexpr float HALF_LOG_2PI = 0.91893853320467274178f;
    constexpr float LN2          = 0.69314718055994530942f;

    const int g      = blockIdx.x * blockDim.x + t;
    const int stride = gridDim.x * blockDim.x;
    // stride*4 % 32 == 0 -> each thread's dim quad is fixed across iterations
    const int dbase  = (g * 4) & (DD - 1);
    const int key    = (dbase >> 2) & 7;

    float a0 = s_kn[dbase + 0][0], a1 = s_kn[dbase + 0][1], a2 = s_kn[dbase + 0][2],
          a3 = s_kn[dbase + 0][3], a4 = s_kn[dbase + 0][4], a5 = s_kn[dbase + 0][5],
          a6 = s_kn[dbase + 0][6];
    float b0 = s_kn[dbase + 1][0], b1 = s_kn[dbase + 1][1], b2 = s_kn[dbase + 1][2],
          b3 = s_kn[dbase + 1][3], b4 = s_kn[dbase + 1][4], b5 = s_kn[dbase + 1][5],
          b6 = s_kn[dbase + 1][6];
    float c0 = s_kn[dbase + 2][0], c1 = s_kn[dbase + 2][1], c2 = s_kn[dbase + 2][2],
          c3 = s_kn[dbase + 2][3], c4 = s_kn[dbase + 2][4], c5 = s_kn[dbase + 2][5],
          c6 = s_kn[dbase + 2][6];
    float e0 = s_kn[dbase + 3][0], e1 = s_kn[dbase + 3][1], e2 = s_kn[dbase + 3][2],
          e3 = s_kn[dbase + 3][3], e4 = s_kn[dbase + 3][4], e5 = s_kn[dbase + 3][5],
          e6 = s_kn[dbase + 3][6];

    const float4* __restrict__ r0 = &s_T[dbase + 0][0];
    const float4* __restrict__ r1 = &s_T[dbase + 1][0];
    const float4* __restrict__ r2 = &s_T[dbase + 2][0];
    const float4* __restrict__ r3 = &s_T[dbase + 3][0];

    auto evalone = [&](float xx,
                       float k0, float k1, float k2, float k3, float k4, float k5, float k6,
                       const float4* __restrict__ row) -> float {
        // tree-shaped accumulation shortens the dependency chain
        int i01 = ((xx >= k0) ? 1 : 0) + ((xx >= k1) ? 1 : 0);
        int i23 = ((xx >= k2) ? 1 : 0) + ((xx >= k3) ? 1 : 0);
        int i45 = ((xx >= k4) ? 1 : 0) + ((xx >= k5) ? 1 : 0);
        int i6  = ((xx >= k6) ? 1 : 0);
        int idx = (i01 + i23) + (i45 + i6);

        const float4 T = row[idx ^ key];   // one ds_read_b128

        const unsigned u1 = __float_as_uint(T.z);
        const unsigned u2 = __float_as_uint(T.w);
        const float ch = __half2float(__ushort_as_half((unsigned short)(u1 & 0xffffu)));
        const float h  = __half2float(__ushort_as_half((unsigned short)(u1 >> 16)));
        const float d0 = __half2float(__ushort_as_half((unsigned short)(u2 & 0xffffu)));
        const float d1 = __half2float(__ushort_as_half((unsigned short)(u2 >> 16)));

        const float xc    = fminf(fmaxf(xx, -TB), TB);
        const float theta = fmaf(xc, T.x, T.y);
        const float delta = h * T.x;                              // h*invw
        const float B     = h * d0;
        const float A     = fmaf(h, delta, -B);                   // h*(delta-d0)
        const float s2    = (d0 + d1) - (delta + delta);
        const float u     = fmaf(-theta, theta, theta);           // θ(1-θ)
        const float den   = fmaf(s2, u, delta);
        const float rden  = __builtin_amdgcn_rcpf(den);
        const float num1  = theta * fmaf(theta, A, B);
        const float zin   = fmaf(num1, rden, ch);
        const float dmd   = delta - d0;
        const float poly  = fmaf(fmaf(s2, theta, dmd + dmd), theta, d0);
        const float ee    = delta * rden;
        const float larg  = poly * (ee * ee);
        const float lg2   = __log2f(larg);
        // outside [-B,B]: θ∈{0,1} to 1ulp -> larg ~= boundary deriv = 1 -> lg2≈0
        const float z  = (fabsf(xx) <= TB) ? zin : xx;
        const float ld = fmaf(lg2, LN2, -HALF_LOG_2PI);
        return fmaf(z * z, -0.5f, ld);
    };

    auto eval4 = [&](f32x4 xv) -> f32x4 {
        f32x4 r;
        r.x = evalone(xv.x, a0, a1, a2, a3, a4, a5, a6, r0);
        r.y = evalone(xv.y, b0, b1, b2, b3, b4, b5, b6, r1);
        r.z = evalone(xv.z, c0, c1, c2, c3, c4, c5, c6, r2);
        r.w = evalone(xv.w, e0, e1, e2, e3, e4, e5, e6, r3);
        return r;
    };

    const f32x4* __restrict__ x4 = reinterpret_cast<const f32x4*>(x);
    f32x4* __restrict__ o4 = reinterpret_cast<f32x4*>(out);

    const int nI = (stride > 0) ? (n4 / stride) : 0;
    if (nI > 0 && (n4 % stride) == 0) {
        // rotated start: waves begin at different points of the same cycle
        const int wv = g >> 6;            // global wave id (uniform per wave)
        int j = wv % nI;
        f32x4 cur = x4[g + j * stride];
        for (int c = 0; c < nI - 1; ++c) {
            int jn = j + 1;
            if (jn == nI) jn = 0;
            const f32x4 nxt = x4[g + jn * stride];   // in flight during eval4(cur)
            __builtin_nontemporal_store(eval4(cur), &o4[g + j * stride]);
            j = jn;
            cur = nxt;
        }
        __builtin_nontemporal_store(eval4(cur), &o4[g + j * stride]);
    } else {
        // general fallback (not hit at N=1048576, D=32)
        int i = g;
        for (; i + stride < n4; i += 2 * stride) {
            const f32x4 xa = x4[i];
            const f32x4 xb = x4[i + stride];
            __builtin_nontemporal_store(eval4(xa), &o4[i]);
            __builtin_nontemporal_store(eval4(xb), &o4[i + stride]);
        }
        for (; i < n4; i += stride) {
            const f32x4 xa = x4[i];
            __builtin_nontemporal_store(eval4(xa), &o4[i]);
        }
    }
}

extern "C" void kernel_launch(void* const* d_in, const int* in_sizes, int n_in,
                              void* d_out, int out_size, void* d_ws, size_t ws_size,
                              hipStream_t stream) {
    const float* x  = (const float*)d_in[0];
    const float* uw = (const float*)d_in[1];
    const float* uh = (const float*)d_in[2];
    const float* ud = (const float*)d_in[3];
    float* out = (float*)d_out;

    const int n4 = in_sizes[0] / 4;                 // N*D/4 float4 elements
    int blocks = (n4 + 255) / 256;
    if (blocks > 2048) blocks = 2048;

    mfb_kernel<<<blocks, 256, 0, stream>>>(x, uw, uh, ud, out, n4);
}